// Round 2
// baseline (505.890 us; speedup 1.0000x reference)
//
#include <hip/hip_runtime.h>
#include <cstdint>

// Problem: out = inputs @ W  (softmax over a constant axis is uniform; GAT collapses to the GEMM)
// inputs: (131072, 256) fp32, W: (256,256) fp32, out: (131072, 256) fp32.
//
// V2r: barrier-free streaming GEMM. All of W (bf16, n-major) lives in LDS (128 KB,
// XOR-swizzled); each wave streams its own A rows global->reg->bf16->MFMA with a
// 1-slab register prefetch pipeline. One __syncthreads() per block (after W stage).
// (Resubmission of round-1 kernel: the round-1 bench was an infra failure, not a
// kernel verdict. Epilogue store loops reordered r-outer for sequential row writes.)

static constexpr int MTOT = 64 * 2048;   // 131072
static constexpr int KDIM = 256;
static constexpr int NDIM = 256;

typedef __bf16 bf16x8 __attribute__((ext_vector_type(8)));
typedef float f32x4 __attribute__((ext_vector_type(4)));

__device__ __forceinline__ uint32_t f2bf_pk(float a, float b) {
    // pack two fp32 -> two bf16 (RNE), lo = a, hi = b
    uint32_t ua = __float_as_uint(a);
    uint32_t ub = __float_as_uint(b);
    ua = ua + 0x7fffu + ((ua >> 16) & 1u);
    ub = ub + 0x7fffu + ((ub >> 16) & 1u);
    return (ua >> 16) | (ub & 0xffff0000u);
}

// --- kernel 1: W (k-major fp32) -> Wt (n-major bf16) in workspace -----------
__global__ void wt_transpose(const float* __restrict__ W, unsigned short* __restrict__ Wt) {
    int n = blockIdx.x;    // 256 blocks
    int k = threadIdx.x;   // 256 threads
    float v = W[k * NDIM + n];           // uncoalesced read; W is 256 KB, L2 absorbs
    uint32_t u = __float_as_uint(v);
    u = u + 0x7fffu + ((u >> 16) & 1u);
    Wt[n * KDIM + k] = (unsigned short)(u >> 16);   // coalesced write
}

// --- kernel 2: streaming GEMM -----------------------------------------------
// 256 blocks x 512 threads (8 waves). Block owns 512 rows; wave owns 64 rows
// = 4 slabs of 16. Full W in LDS. No barriers in the main loop.
__global__ __launch_bounds__(512, 2)
void gat_gemm(const float* __restrict__ A, const unsigned short* __restrict__ Wt,
              float* __restrict__ C) {
    // Flat 256 x 256 bf16 = 128 KB. Row stride 512 B. Bank-conflict fix is the
    // XOR swizzle: byte offset within a row is XORed with (n&7)<<4, so any 8
    // consecutive n-rows read at the same k-chunk hit 8 distinct 16B slots
    // (all 32 banks exactly once per 8 lanes).
    __shared__ alignas(16) unsigned short Bs[256 * 256];

    const int tid  = threadIdx.x;
    const int lane = tid & 63;
    const int wave = tid >> 6;
    const int l15  = lane & 15;
    const int quad = lane >> 4;

    const int mwave = blockIdx.x * 512 + wave * 64;   // wave's first row

    // ---- prefetch A slab 0 (16 rows x 256 k, fp32) BEFORE W staging --------
    // Lane (l15, quad) holds A[row = base+l15][k = ks*32 + quad*8 .. +8) as 2 float4.
    float4 abuf[16];
    {
        const float* ap = A + (size_t)(mwave + l15) * KDIM + quad * 8;
#pragma unroll
        for (int ks = 0; ks < 8; ++ks) {
            abuf[2 * ks]     = *(const float4*)(ap + ks * 32);
            abuf[2 * ks + 1] = *(const float4*)(ap + ks * 32 + 4);
        }
    }

    // ---- stage all of Wt into LDS (swizzled), one barrier ------------------
    // 8192 16B-chunks / 512 threads = 16 per thread; global reads perfectly coalesced.
#pragma unroll
    for (int c = 0; c < 16; ++c) {
        int idx = c * 512 + tid;          // chunk id: n = idx>>5, kc = idx&31
        int n   = idx >> 5;
        int kc  = idx & 31;
        uint4 v = *(const uint4*)(Wt + (size_t)idx * 8);   // linear 16B chunk
        int dst = n * 512 + ((kc * 16) ^ ((n & 7) << 4));  // swizzled byte offset
        *(uint4*)((char*)Bs + dst) = v;
    }
    __syncthreads();

#pragma unroll 1
    for (int s = 0; s < 4; ++s) {
        // ---- convert current slab fp32 -> bf16 A-fragments ----
        bf16x8 af[8];
#pragma unroll
        for (int ks = 0; ks < 8; ++ks) {
            float4 lo = abuf[2 * ks], hi = abuf[2 * ks + 1];
            uint4 w;
            w.x = f2bf_pk(lo.x, lo.y); w.y = f2bf_pk(lo.z, lo.w);
            w.z = f2bf_pk(hi.x, hi.y); w.w = f2bf_pk(hi.z, hi.w);
            af[ks] = *(bf16x8*)&w;
        }

        // ---- prefetch next slab (issues before compute; lands during it) ----
        if (s < 3) {
            const float* ap = A + (size_t)(mwave + (s + 1) * 16 + l15) * KDIM + quad * 8;
#pragma unroll
            for (int ks = 0; ks < 8; ++ks) {
                abuf[2 * ks]     = *(const float4*)(ap + ks * 32);
                abuf[2 * ks + 1] = *(const float4*)(ap + ks * 32 + 4);
            }
        }

        // ---- compute: full N=256 (16 n-frags) x full K=256 (8 k-steps) ----
        f32x4 acc[16];
#pragma unroll
        for (int j = 0; j < 16; ++j) acc[j] = (f32x4)0.0f;

#pragma unroll
        for (int ks = 0; ks < 8; ++ks) {
            const int kbyte = ks * 64 + quad * 16;
#pragma unroll
            for (int j = 0; j < 16; ++j) {
                const int n = j * 16 + l15;
                bf16x8 bf = *(const bf16x8*)((const char*)Bs +
                              n * 512 + (kbyte ^ ((n & 7) << 4)));
                acc[j] = __builtin_amdgcn_mfma_f32_16x16x32_bf16(af[ks], bf, acc[j], 0, 0, 0);
            }
        }

        // ---- store: C/D layout col = l15, row = quad*4 + r ----
        // r outer, j inner: each row's 1 KB written by 16 consecutive 64B stores
        // (sequential addresses -> write-combining into full lines).
        const size_t mbase = (size_t)(mwave + s * 16 + quad * 4);
#pragma unroll
        for (int r = 0; r < 4; ++r) {
            float* cp = C + (mbase + r) * NDIM + l15;
#pragma unroll
            for (int j = 0; j < 16; ++j)
                cp[j * 16] = acc[j][r];
        }
    }
}

extern "C" void kernel_launch(void* const* d_in, const int* in_sizes, int n_in,
                              void* d_out, int out_size, void* d_ws, size_t ws_size,
                              hipStream_t stream) {
    (void)in_sizes; (void)n_in; (void)out_size; (void)ws_size;
    const float* inputs = (const float*)d_in[0];
    const float* W      = (const float*)d_in[1];
    // d_in[2] ('a') is mathematically unused: softmax over a constant axis is uniform,
    // so the output is exactly inputs @ W.
    unsigned short* Wt = (unsigned short*)d_ws;     // 256*256*2 = 128 KB scratch
    float* out = (float*)d_out;

    hipLaunchKernelGGL(wt_transpose, dim3(NDIM), dim3(KDIM), 0, stream, W, Wt);
    hipLaunchKernelGGL(gat_gemm, dim3(MTOT / 512), dim3(512), 0, stream, inputs, Wt, out);
}

// Round 3
// 268.495 us; speedup vs baseline: 1.8842x; 1.8842x over previous
//
#include <hip/hip_runtime.h>
#include <cstdint>

// Problem: out = inputs @ W  (softmax over a constant axis is uniform; GAT collapses to the GEMM)
// inputs: (131072, 256) fp32, W: (256,256) fp32, out: (131072, 256) fp32.
//
// V3: barrier-free streaming GEMM, register-dieted.
// Full W (bf16, n-major, XOR-swizzled) resident in LDS (128 KB); one barrier total.
// 1024-thread blocks (16 waves = 4 waves/SIMD -> real TLP at 128-reg cap).
// Each wave owns 32 rows = 2 slabs of 16; flat 16-chunk loop (2 slabs x 8 k-steps)
// with a 4xfloat4 register ring and depth-2 load lookahead (counted vmcnt).
// V2's failure was register spills (abuf[16]=64 VGPR + acc + af > 128-reg budget ->
// ~600 MB scratch traffic); V3 keeps peak live set ~105 regs.

static constexpr int MTOT = 64 * 2048;   // 131072
static constexpr int KDIM = 256;
static constexpr int NDIM = 256;

typedef __bf16 bf16x8 __attribute__((ext_vector_type(8)));
typedef float f32x4 __attribute__((ext_vector_type(4)));

__device__ __forceinline__ uint32_t f2bf_pk(float a, float b) {
    // pack two fp32 -> two bf16 (RNE), lo = a, hi = b
    uint32_t ua = __float_as_uint(a);
    uint32_t ub = __float_as_uint(b);
    ua = ua + 0x7fffu + ((ua >> 16) & 1u);
    ub = ub + 0x7fffu + ((ub >> 16) & 1u);
    return (ua >> 16) | (ub & 0xffff0000u);
}

// --- kernel 1: W (k-major fp32) -> Wt (n-major bf16) in workspace -----------
__global__ void wt_transpose(const float* __restrict__ W, unsigned short* __restrict__ Wt) {
    int n = blockIdx.x;    // 256 blocks
    int k = threadIdx.x;   // 256 threads
    float v = W[k * NDIM + n];           // uncoalesced read; W is 256 KB, L2 absorbs
    uint32_t u = __float_as_uint(v);
    u = u + 0x7fffu + ((u >> 16) & 1u);
    Wt[n * KDIM + k] = (unsigned short)(u >> 16);   // coalesced write
}

// --- kernel 2: streaming GEMM -----------------------------------------------
// 256 blocks x 1024 threads (16 waves). Block owns 512 rows; wave owns 32 rows.
// Full W in LDS. No barriers in the main loop.
__global__ __launch_bounds__(1024)
void gat_gemm(const float* __restrict__ A, const unsigned short* __restrict__ Wt,
              float* __restrict__ C) {
    // Flat 256 x 256 bf16 = 128 KB. Row stride 512 B. XOR swizzle: byte offset
    // within a row XORed with (n&7)<<4 spreads the 16-lane n-column reads of a
    // ds_read_b128 across all banks (minimum 8-cycle service, no serialization).
    __shared__ alignas(16) unsigned short Bs[256 * 256];

    const int tid  = threadIdx.x;
    const int lane = tid & 63;
    const int wave = tid >> 6;      // 0..15
    const int l15  = lane & 15;
    const int quad = lane >> 4;

    const int rowbase = blockIdx.x * 512 + wave * 32;   // wave's first row

    // ---- stage all of Wt into LDS (swizzled) -------------------------------
    // 8192 16B-chunks / 1024 threads = 8 per thread; global reads coalesced.
#pragma unroll
    for (int c = 0; c < 8; ++c) {
        int idx = c * 1024 + tid;         // chunk id: n = idx>>5, kc = idx&31
        int n   = idx >> 5;
        int kc  = idx & 31;
        uint4 v = *(const uint4*)(Wt + (size_t)idx * 8);
        int dst = n * 512 + ((kc * 16) ^ ((n & 7) << 4));
        *(uint4*)((char*)Bs + dst) = v;
    }

    // ---- prologue: load k-chunks 0,1 of slab 0 (issued before the barrier) --
    // Lane (l15,quad) of chunk c=(s,ks) holds A[rowbase+s*16+l15][ks*32+quad*8 ..+8).
    const float* aln = A + (size_t)(rowbase + l15) * KDIM + quad * 8;
    float4 ring[4];                       // 4 float4 = 16 VGPR, ring of 2 chunks
    ring[0] = *(const float4*)(aln + 0);
    ring[1] = *(const float4*)(aln + 4);
    ring[2] = *(const float4*)(aln + 32);
    ring[3] = *(const float4*)(aln + 36);

    __syncthreads();

    f32x4 acc[16];

    // ---- flat main loop: 16 chunks = 2 slabs x 8 k-steps, fully unrolled ----
#pragma unroll
    for (int c = 0; c < 16; ++c) {
        const int ks = c & 7;

        if (ks == 0) {
#pragma unroll
            for (int j = 0; j < 16; ++j) acc[j] = (f32x4)0.0f;
        }

        // convert current chunk fp32 -> bf16 A-fragment (ring slots are static:
        // c is a compile-time constant under the unroll)
        {
            float4 p = ring[(2 * c) & 3];
            float4 q = ring[(2 * c + 1) & 3];
            uint4 w;
            w.x = f2bf_pk(p.x, p.y); w.y = f2bf_pk(p.z, p.w);
            w.z = f2bf_pk(q.x, q.y); w.w = f2bf_pk(q.z, q.w);
            bf16x8 af = *(bf16x8*)&w;

            // issue chunk c+2 loads into the slots just freed (depth-2 lookahead)
            if (c < 14) {
                const int cn = c + 2;
                const float* ap = aln + (cn >> 3) * 16 * KDIM + (cn & 7) * 32;
                ring[(2 * c) & 3]     = *(const float4*)(ap);
                ring[(2 * c + 1) & 3] = *(const float4*)(ap + 4);
            }

            // 16 MFMAs: full N=256 against LDS-resident W
            const int kbyte = ks * 64 + quad * 16;
#pragma unroll
            for (int j = 0; j < 16; ++j) {
                const int n = j * 16 + l15;
                bf16x8 bf = *(const bf16x8*)((const char*)Bs +
                              n * 512 + (kbyte ^ ((n & 7) << 4)));
                acc[j] = __builtin_amdgcn_mfma_f32_16x16x32_bf16(af, bf, acc[j], 0, 0, 0);
            }
        }

        // ---- slab epilogue: C/D layout col = l15, row = quad*4 + r ----------
        if (ks == 7) {
            const int s = c >> 3;
            const size_t mbase = (size_t)(rowbase + s * 16 + quad * 4);
#pragma unroll
            for (int r = 0; r < 4; ++r) {
                float* cp = C + (mbase + r) * NDIM + l15;
#pragma unroll
                for (int j = 0; j < 16; ++j)
                    cp[j * 16] = acc[j][r];   // 16 consecutive 64B segments/row
            }
        }
    }
}

extern "C" void kernel_launch(void* const* d_in, const int* in_sizes, int n_in,
                              void* d_out, int out_size, void* d_ws, size_t ws_size,
                              hipStream_t stream) {
    (void)in_sizes; (void)n_in; (void)out_size; (void)ws_size;
    const float* inputs = (const float*)d_in[0];
    const float* W      = (const float*)d_in[1];
    // d_in[2] ('a') is mathematically unused: softmax over a constant axis is uniform,
    // so the output is exactly inputs @ W.
    unsigned short* Wt = (unsigned short*)d_ws;     // 256*256*2 = 128 KB scratch
    float* out = (float*)d_out;

    hipLaunchKernelGGL(wt_transpose, dim3(NDIM), dim3(KDIM), 0, stream, W, Wt);
    hipLaunchKernelGGL(gat_gemm, dim3(MTOT / 512), dim3(1024), 0, stream, inputs, Wt, out);
}

// Round 5
// 238.793 us; speedup vs baseline: 2.1185x; 1.1244x over previous
//
#include <hip/hip_runtime.h>
#include <cstdint>

// Problem: out = inputs @ W  (softmax over a constant axis is uniform; GAT collapses to the GEMM)
// inputs: (131072, 256) fp32, W: (256,256) fp32, out: (131072, 256) fp32.
//
// V5 = V4 with the launch-grid bug fixed (512 -> 1024 blocks; V4 left half of C
// unwritten, absmax 5.47 = max|H|).
//
// Design: classic pipelined tile GEMM (T3-minimum schedule).
// BM=256 x BN=128, 1024 threads (16 waves = 8M x 2N, acc[2][4]).
// B-half (128n x 256k bf16, 64 KB, XOR-swizzled) resident in LDS, staged once.
// A double-buffered (2 x 32 KB bf16, XOR-swizzled): issue tile t+1 global loads
// BEFORE tile t's MFMAs, convert+ds_write after, one barrier per K-tile.
// XCD-pair block swizzle: the two N-halves of one M-tile are 8 block-ids apart
// (same XCD, adjacent dispatch) so A is fetched from HBM once.

static constexpr int MTOT = 64 * 2048;   // 131072
static constexpr int KDIM = 256;
static constexpr int NDIM = 256;

typedef __bf16 bf16x8 __attribute__((ext_vector_type(8)));
typedef float f32x4 __attribute__((ext_vector_type(4)));

__device__ __forceinline__ uint32_t f2bf_pk(float a, float b) {
    // pack two fp32 -> two bf16 (RNE), lo = a, hi = b
    uint32_t ua = __float_as_uint(a);
    uint32_t ub = __float_as_uint(b);
    ua = ua + 0x7fffu + ((ua >> 16) & 1u);
    ub = ub + 0x7fffu + ((ub >> 16) & 1u);
    return (ua >> 16) | (ub & 0xffff0000u);
}

// --- kernel 1: W (k-major fp32) -> Wt (n-major bf16) in workspace -----------
__global__ void wt_transpose(const float* __restrict__ W, unsigned short* __restrict__ Wt) {
    int n = blockIdx.x;    // 256 blocks
    int k = threadIdx.x;   // 256 threads
    float v = W[k * NDIM + n];           // uncoalesced read; W is 256 KB, L2 absorbs
    uint32_t u = __float_as_uint(v);
    u = u + 0x7fffu + ((u >> 16) & 1u);
    Wt[n * KDIM + k] = (unsigned short)(u >> 16);   // coalesced write
}

// --- kernel 2: pipelined tile GEMM -------------------------------------------
// grid 1024 = 512 M-tiles x 2 N-halves; block 1024 threads (16 waves).
__global__ __launch_bounds__(1024, 1)
void gat_gemm(const float* __restrict__ A, const unsigned short* __restrict__ Wt,
              float* __restrict__ C) {
    // Bs: 128 n-rows x 256 k bf16, row stride 512 B, byte ^= (n&7)<<4  (64 KB)
    // As: 2 x (256 rows x 64 k bf16), row stride 128 B, byte ^= (row&7)<<4 (2x32 KB)
    __shared__ alignas(16) unsigned short Bs[128 * 256];
    __shared__ alignas(16) unsigned short As[2][256 * 64];

    const int tid  = threadIdx.x;
    const int lane = tid & 63;
    const int wave = tid >> 6;       // 0..15
    const int l15  = lane & 15;
    const int quad = lane >> 4;
    const int wm   = wave & 7;       // 8 M-slots of 32 rows
    const int wn   = wave >> 3;      // 2 N-slots of 64 cols

    // XCD-pair swizzle: mates (same mt, the two nhalves) are 8 ids apart -> same XCD.
    const int b     = blockIdx.x;                 // 0..1023
    const int nhalf = (b >> 3) & 1;
    const int mt    = (b & 7) | ((b >> 4) << 3);  // 0..511 (bijective with nhalf)
    const int bm    = mt * 256;
    const int bn    = nhalf * 128;

    // A staging coords: thread -> (row pair, 8-float segment)
    const int arow = tid >> 3;       // 0..127 (second slab at +128)
    const int aseg = tid & 7;        // 0..7

    // ---- issue A tile-0 loads (coalesced: 8 lanes/row x contiguous 32B) ----
    const float* ap0 = A + (size_t)(bm + arow) * KDIM + aseg * 8;
    float4 a0 = *(const float4*)(ap0);
    float4 a1 = *(const float4*)(ap0 + 4);
    float4 a2 = *(const float4*)(ap0 + 128 * KDIM);
    float4 a3 = *(const float4*)(ap0 + 128 * KDIM + 4);

    // ---- stage resident B-half from Wt (L2-warm: 128 KB total) ----
#pragma unroll
    for (int c = 0; c < 4; ++c) {
        int idx = c * 1024 + tid;         // 0..4095: n = idx>>5, kc = idx&31 (16B units)
        int n   = idx >> 5;
        int kc  = idx & 31;
        uint4 v = *(const uint4*)(Wt + (size_t)(bn + n) * KDIM + kc * 8);
        *(uint4*)((char*)Bs + n * 512 + ((kc * 16) ^ ((n & 7) << 4))) = v;
    }

    // ---- convert + ds_write A tile 0 ----
    {
        uint4 w;
        w.x = f2bf_pk(a0.x, a0.y); w.y = f2bf_pk(a0.z, a0.w);
        w.z = f2bf_pk(a1.x, a1.y); w.w = f2bf_pk(a1.z, a1.w);
        *(uint4*)((char*)&As[0][0] + arow * 128 + ((aseg * 16) ^ ((arow & 7) << 4))) = w;
        int r2 = arow + 128;
        w.x = f2bf_pk(a2.x, a2.y); w.y = f2bf_pk(a2.z, a2.w);
        w.z = f2bf_pk(a3.x, a3.y); w.w = f2bf_pk(a3.z, a3.w);
        *(uint4*)((char*)&As[0][0] + r2 * 128 + ((aseg * 16) ^ ((r2 & 7) << 4))) = w;
    }
    __syncthreads();

    f32x4 acc[2][4];
#pragma unroll
    for (int i = 0; i < 2; ++i)
#pragma unroll
        for (int j = 0; j < 4; ++j)
            acc[i][j] = (f32x4)0.0f;

    // ---- K loop: 4 tiles of BK=64, double-buffered, loads issued before MFMA ----
#pragma unroll
    for (int kt = 0; kt < 4; ++kt) {
        float4 n0, n1, n2, n3;
        if (kt < 3) {   // issue next-tile loads FIRST: latency hides under MFMA
            const float* ap = A + (size_t)(bm + arow) * KDIM + (kt + 1) * 64 + aseg * 8;
            n0 = *(const float4*)(ap);
            n1 = *(const float4*)(ap + 4);
            n2 = *(const float4*)(ap + 128 * KDIM);
            n3 = *(const float4*)(ap + 128 * KDIM + 4);
        }

        // compute tile kt from As[kt&1] and resident Bs
        const char* asb = (const char*)&As[kt & 1][0];
#pragma unroll
        for (int ks = 0; ks < 2; ++ks) {
            bf16x8 af[2];
#pragma unroll
            for (int i = 0; i < 2; ++i) {
                const int row = wm * 32 + i * 16 + l15;
                af[i] = *(const bf16x8*)(asb + row * 128 +
                          ((ks * 64 + quad * 16) ^ ((row & 7) << 4)));
            }
#pragma unroll
            for (int j = 0; j < 4; ++j) {
                const int n = wn * 64 + j * 16 + l15;
                bf16x8 bf = *(const bf16x8*)((const char*)Bs + n * 512 +
                              ((kt * 128 + ks * 64 + quad * 16) ^ ((n & 7) << 4)));
#pragma unroll
                for (int i = 0; i < 2; ++i)
                    acc[i][j] = __builtin_amdgcn_mfma_f32_16x16x32_bf16(af[i], bf, acc[i][j], 0, 0, 0);
            }
        }

        if (kt < 3) {   // convert + write next tile into the other buffer
            char* dst = (char*)&As[(kt + 1) & 1][0];
            uint4 w;
            w.x = f2bf_pk(n0.x, n0.y); w.y = f2bf_pk(n0.z, n0.w);
            w.z = f2bf_pk(n1.x, n1.y); w.w = f2bf_pk(n1.z, n1.w);
            *(uint4*)(dst + arow * 128 + ((aseg * 16) ^ ((arow & 7) << 4))) = w;
            int r2 = arow + 128;
            w.x = f2bf_pk(n2.x, n2.y); w.y = f2bf_pk(n2.z, n2.w);
            w.z = f2bf_pk(n3.x, n3.y); w.w = f2bf_pk(n3.z, n3.w);
            *(uint4*)(dst + r2 * 128 + ((aseg * 16) ^ ((r2 & 7) << 4))) = w;
            __syncthreads();
        }
    }

    // ---- epilogue: C/D layout col = l15, row = quad*4 + r ----
#pragma unroll
    for (int i = 0; i < 2; ++i) {
#pragma unroll
        for (int r = 0; r < 4; ++r) {
            const size_t row = (size_t)(bm + wm * 32 + i * 16 + quad * 4 + r);
            float* cp = C + row * NDIM + bn + wn * 64 + l15;
#pragma unroll
            for (int j = 0; j < 4; ++j)
                cp[j * 16] = acc[i][j][r];   // 64B contiguous per (r,j) store
        }
    }
}

extern "C" void kernel_launch(void* const* d_in, const int* in_sizes, int n_in,
                              void* d_out, int out_size, void* d_ws, size_t ws_size,
                              hipStream_t stream) {
    (void)in_sizes; (void)n_in; (void)out_size; (void)ws_size;
    const float* inputs = (const float*)d_in[0];
    const float* W      = (const float*)d_in[1];
    // d_in[2] ('a') is mathematically unused: softmax over a constant axis is uniform,
    // so the output is exactly inputs @ W.
    unsigned short* Wt = (unsigned short*)d_ws;     // 256*256*2 = 128 KB scratch
    float* out = (float*)d_out;

    hipLaunchKernelGGL(wt_transpose, dim3(NDIM), dim3(KDIM), 0, stream, W, Wt);
    // 512 M-tiles x 2 N-halves = 1024 blocks (V4 bug: this expression evaluated to 512)
    hipLaunchKernelGGL(gat_gemm, dim3((MTOT / 256) * 2), dim3(1024), 0, stream, inputs, Wt, out);
}

// Round 6
// 236.996 us; speedup vs baseline: 2.1346x; 1.0076x over previous
//
#include <hip/hip_runtime.h>
#include <cstdint>

// Problem: out = inputs @ W  (softmax over a constant axis is uniform; GAT collapses to the GEMM)
// inputs: (131072, 256) fp32, W: (256,256) fp32, out: (131072, 256) fp32.
//
// V6: V5 + T4 (counted vmcnt, never drain) + depth-2 register lookahead.
// - BM=256 x BN=128, 1024 threads (16 waves = 8M x 2N), resident B-half in LDS.
// - Raw s_barrier + explicit lgkmcnt(0) (no __syncthreads vmcnt(0) drain):
//   A-tile loads stay in flight ACROSS barriers -> memory pipe duty cycle ~100%.
// - Iteration kt: issue tile kt+2 -> regs; MFMA tile kt from As[kt&1];
//   convert+ds_write tile kt+1 (loaded a full iteration ago -> waits vmcnt(4), not 0).
// - A staging is chunk-contiguous: each wave-load-instruction reads 1 KB contiguous.
//
// V5 post-mortem: depth-1 pipeline + __syncthreads drain -> zero bytes in flight
// once per K-tile -> 2.35 TB/s (37% duty) regardless of structure.

static constexpr int MTOT = 64 * 2048;   // 131072
static constexpr int KDIM = 256;
static constexpr int NDIM = 256;

typedef __bf16 bf16x8 __attribute__((ext_vector_type(8)));
typedef float f32x4 __attribute__((ext_vector_type(4)));

__device__ __forceinline__ uint32_t f2bf_pk(float a, float b) {
    // pack two fp32 -> two bf16 (RNE), lo = a, hi = b
    uint32_t ua = __float_as_uint(a);
    uint32_t ub = __float_as_uint(b);
    ua = ua + 0x7fffu + ((ua >> 16) & 1u);
    ub = ub + 0x7fffu + ((ub >> 16) & 1u);
    return (ua >> 16) | (ub & 0xffff0000u);
}

// --- kernel 1: W (k-major fp32) -> Wt (n-major bf16) in workspace -----------
__global__ void wt_transpose(const float* __restrict__ W, unsigned short* __restrict__ Wt) {
    int n = blockIdx.x;    // 256 blocks
    int k = threadIdx.x;   // 256 threads
    float v = W[k * NDIM + n];           // uncoalesced read; W is 256 KB, L2 absorbs
    uint32_t u = __float_as_uint(v);
    u = u + 0x7fffu + ((u >> 16) & 1u);
    Wt[n * KDIM + k] = (unsigned short)(u >> 16);   // coalesced write
}

// --- kernel 2: pipelined tile GEMM -------------------------------------------
// grid 1024 = 512 M-tiles x 2 N-halves; block 1024 threads (16 waves).
__global__ __launch_bounds__(1024, 1)
void gat_gemm(const float* __restrict__ A, const unsigned short* __restrict__ Wt,
              float* __restrict__ C) {
    // Bs: 128 n-rows x 256 k bf16, row stride 512 B, byte ^= (n&7)<<4  (64 KB)
    // As: 2 x (256 rows x 64 k bf16), row stride 128 B, byte ^= (row&7)<<4 (2x32 KB)
    __shared__ alignas(16) unsigned short Bs[128 * 256];
    __shared__ alignas(16) unsigned short As[2][256 * 64];

    const int tid  = threadIdx.x;
    const int lane = tid & 63;
    const int wave = tid >> 6;       // 0..15
    const int l15  = lane & 15;
    const int quad = lane >> 4;
    const int wm   = wave & 7;       // 8 M-slots of 32 rows
    const int wn   = wave >> 3;      // 2 N-slots of 64 cols

    // XCD-pair swizzle: mates (same mt, the two nhalves) are 8 ids apart -> same XCD.
    const int b     = blockIdx.x;                 // 0..1023
    const int nhalf = (b >> 3) & 1;
    const int mt    = (b & 7) | ((b >> 4) << 3);  // 0..511 (bijective with nhalf)
    const int bm    = mt * 256;
    const int bn    = nhalf * 128;

    // A staging: 16-B chunk c of a 256x64 tile -> row c>>4, float-offset (c&15)*4.
    // Thread t takes chunks {i*1024 + t}: per instruction a wave reads 1 KB contiguous.
    const int arow = tid >> 4;       // 0..63 (row within 64-row group i)
    const int acol = (tid & 15) * 4; // float offset in the 64-float tile row
    const int as8  = (tid & 15) * 8; // byte slot of the converted 8-B chunk

    f32x4 acc[2][4];
#pragma unroll
    for (int i = 0; i < 2; ++i)
#pragma unroll
        for (int j = 0; j < 4; ++j)
            acc[i][j] = (f32x4)0.0f;

    auto issueA = [&](int kt, float4 (&R)[4]) {
#pragma unroll
        for (int i = 0; i < 4; ++i)
            R[i] = *(const float4*)(A + (size_t)(bm + i * 64 + arow) * KDIM + kt * 64 + acol);
    };
    auto writeA = [&](unsigned short* dst, float4 (&R)[4]) {
#pragma unroll
        for (int i = 0; i < 4; ++i) {
            const int r = i * 64 + arow;
            uint2 w;
            w.x = f2bf_pk(R[i].x, R[i].y);
            w.y = f2bf_pk(R[i].z, R[i].w);
            *(uint2*)((char*)dst + r * 128 + (as8 ^ ((r & 7) << 4))) = w;
        }
    };
    auto compute = [&](const unsigned short* asrc, int kt) {
        const char* asb = (const char*)asrc;
#pragma unroll
        for (int ks = 0; ks < 2; ++ks) {
            bf16x8 af[2];
#pragma unroll
            for (int i = 0; i < 2; ++i) {
                const int row = wm * 32 + i * 16 + l15;
                af[i] = *(const bf16x8*)(asb + row * 128 +
                          ((ks * 64 + quad * 16) ^ ((row & 7) << 4)));
            }
#pragma unroll
            for (int j = 0; j < 4; ++j) {
                const int n = wn * 64 + j * 16 + l15;
                bf16x8 bf = *(const bf16x8*)((const char*)Bs + n * 512 +
                              ((kt * 128 + ks * 64 + quad * 16) ^ ((n & 7) << 4)));
#pragma unroll
                for (int i = 0; i < 2; ++i)
                    acc[i][j] = __builtin_amdgcn_mfma_f32_16x16x32_bf16(af[i], bf, acc[i][j], 0, 0, 0);
            }
        }
    };
    // Non-draining barrier: own LDS ops done (lgkmcnt(0)), but global loads stay
    // in flight (no vmcnt(0) -- the whole point vs __syncthreads()).
    auto wavebar = [&]() {
        asm volatile("s_waitcnt lgkmcnt(0)" ::: "memory");
        __builtin_amdgcn_s_barrier();
        asm volatile("" ::: "memory");   // compiler-only fence: no hoist above barrier
    };

    // ---- prologue ----------------------------------------------------------
    // B-stage loads first (oldest in vmcnt queue), then A tiles 0,1: the Bs
    // ds_write then waits only vmcnt(8) (A loads remain outstanding).
    uint4 bv[4];
#pragma unroll
    for (int c = 0; c < 4; ++c) {
        const int idx = c * 1024 + tid;           // n = idx>>5, kc = idx&31 (16B units)
        bv[c] = *(const uint4*)(Wt + (size_t)(bn + (idx >> 5)) * KDIM + (idx & 31) * 8);
    }
    float4 R0[4], R1[4];
    issueA(0, R0);
    issueA(1, R1);
#pragma unroll
    for (int c = 0; c < 4; ++c) {
        const int idx = c * 1024 + tid;
        const int n = idx >> 5, kc = idx & 31;
        *(uint4*)((char*)Bs + n * 512 + ((kc * 16) ^ ((n & 7) << 4))) = bv[c];
    }
    writeA(&As[0][0], R0);    // waits vmcnt(4): tile-1 loads stay in flight
    wavebar();

    // ---- main loop: 4 K-tiles, depth-2 lookahead ---------------------------
    // iter kt: issue tile kt+2 -> R[kt&1]; compute As[kt&1]; convert tile kt+1
    // (R[(kt+1)&1], loaded one full iteration ago) -> As[(kt+1)&1]; barrier.
#pragma unroll
    for (int kt = 0; kt < 4; ++kt) {
        if (kt < 2) {
            if ((kt & 1) == 0) issueA(kt + 2, R0); else issueA(kt + 2, R1);
        }
        compute(&As[kt & 1][0], kt);
        if (kt < 3) {
            if ((kt & 1) == 0) writeA(&As[1][0], R1); else writeA(&As[0][0], R0);
            wavebar();
        }
    }

    // ---- epilogue: C/D layout col = l15, row = quad*4 + r ------------------
#pragma unroll
    for (int i = 0; i < 2; ++i) {
#pragma unroll
        for (int r = 0; r < 4; ++r) {
            const size_t row = (size_t)(bm + wm * 32 + i * 16 + quad * 4 + r);
            float* cp = C + row * NDIM + bn + wn * 64 + l15;
#pragma unroll
            for (int j = 0; j < 4; ++j)
                cp[j * 16] = acc[i][j][r];   // 64B contiguous per (r,j) store
        }
    }
}

extern "C" void kernel_launch(void* const* d_in, const int* in_sizes, int n_in,
                              void* d_out, int out_size, void* d_ws, size_t ws_size,
                              hipStream_t stream) {
    (void)in_sizes; (void)n_in; (void)out_size; (void)ws_size;
    const float* inputs = (const float*)d_in[0];
    const float* W      = (const float*)d_in[1];
    // d_in[2] ('a') is mathematically unused: softmax over a constant axis is uniform,
    // so the output is exactly inputs @ W.
    unsigned short* Wt = (unsigned short*)d_ws;     // 256*256*2 = 128 KB scratch
    float* out = (float*)d_out;

    hipLaunchKernelGGL(wt_transpose, dim3(NDIM), dim3(KDIM), 0, stream, W, Wt);
    // 512 M-tiles x 2 N-halves = 1024 blocks
    hipLaunchKernelGGL(gat_gemm, dim3((MTOT / 256) * 2), dim3(1024), 0, stream, inputs, Wt, out);
}